// Round 1
// baseline (299.731 us; speedup 1.0000x reference)
//
#include <hip/hip_runtime.h>
#include <stdint.h>
#include <stddef.h>

// Causal GQA prefill attention, MI355X gfx950.
// Round 4: single-kernel, zero-workspace version. The round-3 two-kernel
// pipeline (prepack -> d_ws -> attn) tripped the harness's launch_once-vs-graph
// output tripwire: d_ws is re-poisonable state between graph nodes, so the
// kernel must be a pure function of d_in per launch. This version stages K/V
// fp32 -> bf16 in-kernel (reg-staged, double-buffered LDS, one barrier per
// 64-key tile), keeping the verified math pipeline:
//
//   S^T = K*Q^T via mfma_16x16x32_bf16: C-layout (row=key=quad*4+r, col=q=l15)
//   equals the A-operand layout of mfma_16x16x16bf16_1k, so softmaxed P feeds
//   PV straight from registers (no LDS round-trip, no transposes).
//
// LDS tile image (32768 B per 64-key tile, double buffered = 64 KB):
//   K-part (16384 B): chunk c in 0..15, key r in 0..63:
//       bytes [c*1024 + r*16] = K[r][c*8 .. c*8+7]   (bf16x8)
//   V-part (16384 B): unit u in 0..15, d in 0..127:
//       bytes [16384 + u*1024 + d*8] = V[u*4 .. u*4+3][d]  (V^T, bf16x4)
// Row strides of 16/8 B inside 1KB blocks -> QK b128 reads and PV b64 reads
// are <=2-way per quarter-wave (free per m136).

#define S_LEN   2048
#define HQ      32
#define HKV     8
#define DH      128
#define QSTRIDE (HQ*DH)
#define KSTRIDE (HKV*DH)
// (1/sqrt(128)) * log2(e): softmax in exp2 space
#define SCALE_L2 0.12751139830213113f

#define KTILE      64
#define NTILES     (S_LEN/KTILE)          // 32
#define TILE_ELEMS 16384                  // bf16 elems per tile image (32 KB)
#define KPART      8192                   // elems in K-part

typedef __bf16 bf16;
typedef short        s16x4 __attribute__((ext_vector_type(4)));
typedef short        s16x8 __attribute__((ext_vector_type(8)));
typedef float        f32x4 __attribute__((ext_vector_type(4)));
typedef unsigned int u32x2 __attribute__((ext_vector_type(2)));
typedef unsigned int u32x4 __attribute__((ext_vector_type(4)));

__device__ __forceinline__ unsigned int pk2(float a, float b) {
  union { bf16 h[2]; unsigned int u; } x;
  x.h[0] = (bf16)a; x.h[1] = (bf16)b;    // fptrunc = RNE
  return x.u;
}

__global__ __launch_bounds__(512, 4)
void attn_fwd(const float* __restrict__ qg, const float* __restrict__ kg,
              const float* __restrict__ vg, float* __restrict__ og) {
  __shared__ bf16 smem[2*TILE_ELEMS];    // 65,536 B, double-buffered

  const int tid   = threadIdx.x;
  const int lane  = tid & 63;
  const int wave  = tid >> 6;            // 8 waves/block
  const int l15   = lane & 15;
  const int quad  = lane >> 4;
  const int pairp = blockIdx.x;          // 0..7
  const int h     = blockIdx.y;          // 0..31
  const int b     = blockIdx.z;          // 0..1
  const int hkv   = h >> 2;

  // staging roles: 512 threads cover the 64x128 K tile and 64x128 V tile
  const int fk_key = tid >> 3, fk_cg = tid & 7;      // K: 2 chunks / thread
  const int fv_u   = tid & 15, fv_dq = tid >> 4;     // V: unit, d-quad
  float4 fkx[4], fvx[4];

  auto load_regs = [&](int t) {
    const float* kp = kg + (size_t)(b*S_LEN + t*KTILE + fk_key)*KSTRIDE
                         + hkv*DH + fk_cg*16;
#pragma unroll
    for (int i = 0; i < 4; ++i) fkx[i] = ((const float4*)kp)[i];
    const int d0 = fv_dq*4;
#pragma unroll
    for (int j = 0; j < 4; ++j)
      fvx[j] = *(const float4*)(vg + (size_t)(b*S_LEN + t*KTILE + fv_u*4 + j)*KSTRIDE
                                   + hkv*DH + d0);
  };
  auto store_tile = [&](int bi) {
    bf16* kb = smem + bi*TILE_ELEMS;
#pragma unroll
    for (int ii = 0; ii < 2; ++ii) {
      u32x4 w;
      w[0] = pk2(fkx[2*ii].x,   fkx[2*ii].y);   w[1] = pk2(fkx[2*ii].z,   fkx[2*ii].w);
      w[2] = pk2(fkx[2*ii+1].x, fkx[2*ii+1].y); w[3] = pk2(fkx[2*ii+1].z, fkx[2*ii+1].w);
      *(u32x4*)(kb + (fk_cg*2 + ii)*512 + fk_key*8) = w;
    }
    bf16* vb = kb + KPART;
    const float* g0 = (const float*)&fvx[0];
    const float* g1 = (const float*)&fvx[1];
    const float* g2 = (const float*)&fvx[2];
    const float* g3 = (const float*)&fvx[3];
#pragma unroll
    for (int i = 0; i < 4; ++i) {
      u32x2 w;
      w[0] = pk2(g0[i], g1[i]);
      w[1] = pk2(g2[i], g3[i]);
      *(u32x2*)(vb + fv_u*512 + (fv_dq*4 + i)*4) = w;
    }
  };

  f32x4 oacc[8];
  float m_run, l_run;
  u32x4 qf[4];

  const int qbs[2] = { pairp, 15 - pairp };     // balanced: 34 steps total
  load_regs(0);

  int gs = 0;                                   // flat step counter
#pragma unroll 1
  for (int item = 0; item < 2; ++item) {
    const int qblk = qbs[item];
    const int qw   = qblk*128 + wave*16;        // this wave's 16 q-rows
    const int nst  = qblk*2 + 2;

    // Q fragments (B-operand of S^T = K*Q^T), scale*log2e folded in
    {
      const float* qp = qg + (size_t)(b*S_LEN + qw + l15)*QSTRIDE
                           + h*DH + quad*8;
#pragma unroll
      for (int c = 0; c < 4; ++c) {
        const float4 a4 = ((const float4*)(qp + c*32))[0];
        const float4 b4 = ((const float4*)(qp + c*32))[1];
        u32x4 w;
        w[0] = pk2(a4.x*SCALE_L2, a4.y*SCALE_L2);
        w[1] = pk2(a4.z*SCALE_L2, a4.w*SCALE_L2);
        w[2] = pk2(b4.x*SCALE_L2, b4.y*SCALE_L2);
        w[3] = pk2(b4.z*SCALE_L2, b4.w*SCALE_L2);
        qf[c] = w;
      }
    }
#pragma unroll
    for (int nd = 0; nd < 8; ++nd) oacc[nd] = (f32x4){0.f, 0.f, 0.f, 0.f};
    m_run = -3e38f; l_run = 0.f;

#pragma unroll 1
    for (int i = 0; i < nst; ++i, ++gs) {
      const int k0  = i*KTILE;
      const int buf = gs & 1;
      store_tile(buf);                         // waits vmcnt on prefetch regs
      __syncthreads();                         // tile `gs` visible in buf
      // prefetch next step's tile into registers (overlaps compute below)
      const bool more  = (i + 1 < nst);
      const bool cross = (!more) && (item == 0);
      if (more)       load_regs(i + 1);
      else if (cross) load_regs(0);

      if (k0 <= qw + 15) {                     // wave-uniform causal skip
        const bf16* kb = smem + buf*TILE_ELEMS;
        const bf16* vb = kb + KPART;

        // ---- S^T = K_tile * Q^T : 4 key-subtiles ----
        f32x4 sacc[4];
#pragma unroll
        for (int mt = 0; mt < 4; ++mt) sacc[mt] = (f32x4){0.f, 0.f, 0.f, 0.f};
#pragma unroll
        for (int c = 0; c < 4; ++c) {
#pragma unroll
          for (int mt = 0; mt < 4; ++mt) {
            const u32x4 af = *(const u32x4*)(kb + (c*4 + quad)*512
                                                + (mt*16 + l15)*8);
            sacc[mt] = __builtin_amdgcn_mfma_f32_16x16x32_bf16(
                __builtin_bit_cast(s16x8, af), __builtin_bit_cast(s16x8, qf[c]),
                sacc[mt], 0, 0, 0);
          }
        }

        // ---- online softmax in exp2 space (per-lane state: q = qw + l15) --
        const bool needmask = (k0 + KTILE - 1 > qw);   // wave-uniform
        const int  qgl = qw + l15;
        float tmax = -3e38f;
#pragma unroll
        for (int mt = 0; mt < 4; ++mt)
#pragma unroll
          for (int r = 0; r < 4; ++r) {
            float sv = sacc[mt][r];
            if (needmask) {
              const int key = k0 + mt*16 + quad*4 + r;
              sv = (key <= qgl) ? sv : -3e38f;
            }
            sacc[mt][r] = sv;
            tmax = fmaxf(tmax, sv);
          }
        tmax = fmaxf(tmax, __shfl_xor(tmax, 16));
        tmax = fmaxf(tmax, __shfl_xor(tmax, 32));
        const float mnew  = fmaxf(m_run, tmax);
        const float alpha = __builtin_amdgcn_exp2f(m_run - mnew);
        m_run = mnew;
        float rsum = 0.f;
#pragma unroll
        for (int mt = 0; mt < 4; ++mt)
#pragma unroll
          for (int r = 0; r < 4; ++r) {
            const float e = __builtin_amdgcn_exp2f(sacc[mt][r] - mnew);
            sacc[mt][r] = e;
            rsum += e;
          }
        rsum += __shfl_xor(rsum, 16);
        rsum += __shfl_xor(rsum, 32);
        l_run = l_run*alpha + rsum;

        s16x4 pa[4];
#pragma unroll
        for (int mt = 0; mt < 4; ++mt) {       // P already in A-layout
          union { bf16 hh[4]; s16x4 s; } u;
#pragma unroll
          for (int r = 0; r < 4; ++r) u.hh[r] = (bf16)sacc[mt][r];
          pa[mt] = u.s;
        }

        // ---- rescale O rows (row = quad*4 + r) ----
#pragma unroll
        for (int r = 0; r < 4; ++r) {
          const float a = __shfl(alpha, (lane & 48) | (quad*4 + r));
#pragma unroll
          for (int nd = 0; nd < 8; ++nd) oacc[nd][r] *= a;
        }

        // ---- O += P * V ----
#pragma unroll
        for (int kt = 0; kt < 4; ++kt)
#pragma unroll
          for (int nd = 0; nd < 8; ++nd) {
            const s16x4 bv = *(const s16x4*)(vb + (kt*4 + quad)*512
                                                + (nd*16 + l15)*4);
            oacc[nd] = __builtin_amdgcn_mfma_f32_16x16x16bf16_1k(
                pa[kt], bv, oacc[nd], 0, 0, 0);
          }
      }
    }

    // ---- epilogue: O / l, fp32 store ----
#pragma unroll
    for (int r = 0; r < 4; ++r) {
      const float li  = __shfl(l_run, (lane & 48) | (quad*4 + r));
      const float inv = 1.0f / li;
      const size_t base = (size_t)(b*S_LEN + qw + quad*4 + r)*QSTRIDE
                        + h*DH + l15;
#pragma unroll
      for (int nd = 0; nd < 8; ++nd)
        og[base + nd*16] = oacc[nd][r] * inv;
    }
  }
}

extern "C" void kernel_launch(void* const* d_in, const int* in_sizes, int n_in,
                              void* d_out, int out_size, void* d_ws, size_t ws_size,
                              hipStream_t stream) {
  const float* q = (const float*)d_in[0];
  const float* k = (const float*)d_in[1];
  const float* v = (const float*)d_in[2];
  float* out = (float*)d_out;
  (void)d_ws; (void)ws_size;
  dim3 grid(8, HQ, 2);       // 8 balanced pairs x 32 heads x 2 batches
  dim3 block(512);
  attn_fwd<<<grid, block, 0, stream>>>(q, k, v, out);
}